// Round 4
// baseline (1013.428 us; speedup 1.0000x reference)
//
#include <hip/hip_runtime.h>

// MS1: 64-layer reversible net, fused single-kernel recurrence.
//   Z += H*tanh(Y @ K_j^T + b_j[256:]);  Y += H*tanh(b_j[:256] - Z @ K_j)
// R4: B fragments loaded DIRECTLY global->registers, 4-tile-deep rotating
// prefetch (counted vmcnt by compiler). LDS holds only Y/Z state (64 KB).
// ONE raw barrier per half-layer (the state-transpose handoff) -> waves run
// un-lockstepped. 256 blocks x 32 rows, 1024 threads (16 waves); wave w owns
// n-cols [16w,16w+16) x both m-tiles. 3-pass f16 Ozaki MFMA (AhBh+AlBh+AhBl).

typedef _Float16 f16x8 __attribute__((ext_vector_type(8)));
typedef _Float16 f16x2 __attribute__((ext_vector_type(2)));
typedef float    f32x4 __attribute__((ext_vector_type(4)));

#define H_STEP 0.015625f   // 1/64

__device__ __forceinline__ float fast_tanh(float x) {
    float xc = fminf(fmaxf(x, -9.0f), 9.0f);
    float t  = __builtin_amdgcn_exp2f(xc * 2.8853900817779268f); // 2x*log2(e)
    return (t - 1.0f) * __builtin_amdgcn_rcpf(t + 1.0f);
}

// state LDS index with XOR swizzle (16B-granular column rotation per row)
__device__ __forceinline__ int swz(int m, int k) {
    return (m << 8) + (k ^ ((m & 7) << 3));
}

// ---------------- prep: K[a][b][j] -> fragment-friendly half arrays ----------
// B1[j][n][k] = K[n][k][j]  (for Y @ K^T);  B2[j][n][k] = K[k][n][j]  (Z @ K)
__global__ __launch_bounds__(256) void prep_split(
    const float* __restrict__ K,
    _Float16* __restrict__ B1h, _Float16* __restrict__ B1l,
    _Float16* __restrict__ B2h, _Float16* __restrict__ B2l)
{
    __shared__ float tile[32][33][9];
    const int a0 = (blockIdx.x & 7) << 5;
    const int b0 = ((blockIdx.x >> 3) & 7) << 5;
    const int j0 = (blockIdx.x >> 6) << 3;
    const int t = threadIdx.x;

    for (int idx = t; idx < 8192; idx += 256) {
        const int jj = idx & 7, bb = (idx >> 3) & 31, aa = idx >> 8;
        tile[aa][bb][jj] = K[((size_t)(a0 + aa) * 256 + (b0 + bb)) * 64 + (j0 + jj)];
    }
    __syncthreads();

    for (int idx = t; idx < 4096; idx += 256) {
        const int p = idx & 15, aa = (idx >> 4) & 31, jj = idx >> 9;
        const float f0 = tile[aa][2*p][jj], f1 = tile[aa][2*p+1][jj];
        const _Float16 h0 = (_Float16)f0, h1 = (_Float16)f1;
        const f16x2 hv = {h0, h1};
        const f16x2 lv = {(_Float16)(f0 - (float)h0), (_Float16)(f1 - (float)h1)};
        const size_t off = ((size_t)(j0 + jj) * 256 + (a0 + aa)) * 256 + (b0 + 2*p);
        *(f16x2*)(B1h + off) = hv;
        *(f16x2*)(B1l + off) = lv;
    }
    for (int idx = t; idx < 4096; idx += 256) {
        const int p = idx & 15, bb = (idx >> 4) & 31, jj = idx >> 9;
        const float f0 = tile[2*p][bb][jj], f1 = tile[2*p+1][bb][jj];
        const _Float16 h0 = (_Float16)f0, h1 = (_Float16)f1;
        const f16x2 hv = {h0, h1};
        const f16x2 lv = {(_Float16)(f0 - (float)h0), (_Float16)(f1 - (float)h1)};
        const size_t off = ((size_t)(j0 + jj) * 256 + (b0 + bb)) * 256 + (a0 + 2*p);
        *(f16x2*)(B2h + off) = hv;
        *(f16x2*)(B2l + off) = lv;
    }
}

// one k-tile: consume slot (loaded 4 kt ago), refill it for kt+4, 6 MFMAs.
#define KT_STEP(KT, PH, PL, SH, SL, TOFF)                                      \
    {                                                                          \
        const f16x8 bh = PH, bl = PL;                                          \
        PH = *(const f16x8*)((SH) + boff + (TOFF));                            \
        PL = *(const f16x8*)((SL) + boff + (TOFF));                            \
        const int k0 = (KT) * 32 + hi4 * 8;                                    \
        const f16x8 ah0 = *(const f16x8*)(lds + stA + swz(l15, k0));           \
        const f16x8 al0 = *(const f16x8*)(lds + stA + 8192 + swz(l15, k0));    \
        const f16x8 ah1 = *(const f16x8*)(lds + stA + swz(16 + l15, k0));      \
        const f16x8 al1 = *(const f16x8*)(lds + stA + 8192 + swz(16 + l15, k0));\
        acc0 = __builtin_amdgcn_mfma_f32_16x16x32_f16(ah0, bh, acc0, 0, 0, 0); \
        acc1 = __builtin_amdgcn_mfma_f32_16x16x32_f16(ah1, bh, acc1, 0, 0, 0); \
        acc0 = __builtin_amdgcn_mfma_f32_16x16x32_f16(al0, bh, acc0, 0, 0, 0); \
        acc1 = __builtin_amdgcn_mfma_f32_16x16x32_f16(al1, bh, acc1, 0, 0, 0); \
        acc0 = __builtin_amdgcn_mfma_f32_16x16x32_f16(ah0, bl, acc0, 0, 0, 0); \
        acc1 = __builtin_amdgcn_mfma_f32_16x16x32_f16(ah1, bl, acc1, 0, 0, 0); \
    }

// one half-layer: 8 k-tiles + epilogue + single raw barrier.
template<bool NEG>
__device__ __forceinline__ void phase(
    _Float16* lds, const int stA, const int stO,
    const _Float16* __restrict__ Bh,  const _Float16* __restrict__ Bl,
    const _Float16* __restrict__ BhN, const _Float16* __restrict__ BlN,
    const float* __restrict__ bias,      // pre-offset: bvec + featbase*64 + j
    float (&M)[2][4],
    f16x8& p0h, f16x8& p0l, f16x8& p1h, f16x8& p1l,
    f16x8& p2h, f16x8& p2l, f16x8& p3h, f16x8& p3l,
    const int boff, const int n, const int l15, const int hi4)
{
    const float bv = bias[(size_t)n * 64];
    f32x4 acc0 = {0.f,0.f,0.f,0.f}, acc1 = {0.f,0.f,0.f,0.f};

    KT_STEP(0, p0h, p0l, Bh,  Bl,  4 * 32)
    KT_STEP(1, p1h, p1l, Bh,  Bl,  5 * 32)
    KT_STEP(2, p2h, p2l, Bh,  Bl,  6 * 32)
    KT_STEP(3, p3h, p3l, Bh,  Bl,  7 * 32)
    KT_STEP(4, p0h, p0l, BhN, BlN, 0 * 32)
    KT_STEP(5, p1h, p1l, BhN, BlN, 1 * 32)
    KT_STEP(6, p2h, p2l, BhN, BlN, 2 * 32)
    KT_STEP(7, p3h, p3l, BhN, BlN, 3 * 32)

    // epilogue: master += H*tanh(bias +/- acc), re-split state hi/lo to LDS
#pragma unroll
    for (int mt = 0; mt < 2; ++mt) {
#pragma unroll
        for (int q = 0; q < 4; ++q) {
            const float a = mt ? acc1[q] : acc0[q];
            const float x = NEG ? (bv - a) : (a + bv);
            const float v = M[mt][q] + H_STEP * fast_tanh(x);
            M[mt][q] = v;
            const _Float16 vh = (_Float16)v;
            const int m = mt * 16 + hi4 * 4 + q;
            const int o = swz(m, n);
            lds[stO + o] = vh;
            lds[stO + 8192 + o] = (_Float16)(v - (float)vh);
        }
    }
    // all my LDS state writes done -> signal; raw barrier (vmcnt stays live!)
    asm volatile("s_waitcnt lgkmcnt(0)" ::: "memory");
    __builtin_amdgcn_s_barrier();
    __builtin_amdgcn_sched_barrier(0);
}

__global__ __launch_bounds__(1024, 4) void ms1_main(
    const float* __restrict__ Y0,
    const float* __restrict__ bvec,
    const _Float16* __restrict__ B1h, const _Float16* __restrict__ B1l,
    const _Float16* __restrict__ B2h, const _Float16* __restrict__ B2l,
    float* __restrict__ out)
{
    // state only: Y hi/lo @0/8192, Z hi/lo @16384/24576  (64 KB)
    __shared__ _Float16 lds[32768];
#define ST_Y 0
#define ST_Z 16384

    const int tid  = threadIdx.x;
    const int lane = tid & 63, w = tid >> 6;   // 16 waves = 16 n-tiles
    const int l15 = lane & 15, hi4 = lane >> 4;
    const int n    = w * 16 + l15;             // this lane's output column
    const int boff = n * 256 + hi4 * 8;        // B fragment base (halfs)
    const size_t row0 = (size_t)blockIdx.x * 32;

    float Ym[2][4], Zm[2][4];                  // fp32 masters [mt][q]

#pragma unroll
    for (int mt = 0; mt < 2; ++mt) {
#pragma unroll
        for (int q = 0; q < 4; ++q) {
            const int m = mt * 16 + hi4 * 4 + q;
            const size_t base = (row0 + m) * 512;
            const float y = Y0[base + n];
            const float z = Y0[base + 256 + n];
            Ym[mt][q] = y; Zm[mt][q] = z;
            const _Float16 yh = (_Float16)y;
            const int o = swz(m, n);
            lds[ST_Y + o] = yh;
            lds[ST_Y + 8192 + o] = (_Float16)(y - (float)yh);
        }
    }
    __syncthreads();

    // prologue: prefetch phase-0 k-tiles 0..3 into the 4 rotating slots
    f16x8 p0h = *(const f16x8*)(B1h + boff);
    f16x8 p0l = *(const f16x8*)(B1l + boff);
    f16x8 p1h = *(const f16x8*)(B1h + boff + 32);
    f16x8 p1l = *(const f16x8*)(B1l + boff + 32);
    f16x8 p2h = *(const f16x8*)(B1h + boff + 64);
    f16x8 p2l = *(const f16x8*)(B1l + boff + 64);
    f16x8 p3h = *(const f16x8*)(B1h + boff + 96);
    f16x8 p3l = *(const f16x8*)(B1l + boff + 96);

    for (int j = 0; j < 64; ++j) {
        const size_t jb  = (size_t)j << 16;
        const size_t jbn = (j < 63) ? ((size_t)(j + 1) << 16) : 0; // wrap: dead
        // Z += H*tanh(Y @ K^T + b[256:])   (A=Y, next B = B2 of same j)
        phase<false>(lds, ST_Y, ST_Z, B1h + jb, B1l + jb, B2h + jb, B2l + jb,
                     bvec + 256 * 64 + j, Zm,
                     p0h, p0l, p1h, p1l, p2h, p2l, p3h, p3l,
                     boff, n, l15, hi4);
        // Y += H*tanh(b[:256] - Z @ K)     (A=Z, next B = B1 of j+1)
        phase<true>(lds, ST_Z, ST_Y, B2h + jb, B2l + jb, B1h + jbn, B1l + jbn,
                    bvec + j, Ym,
                    p0h, p0l, p1h, p1l, p2h, p2l, p3h, p3l,
                    boff, n, l15, hi4);
    }

#pragma unroll
    for (int mt = 0; mt < 2; ++mt) {
#pragma unroll
        for (int q = 0; q < 4; ++q) {
            const int m = mt * 16 + hi4 * 4 + q;
            const size_t base = (row0 + m) * 512;
            out[base + n]       = Ym[mt][q];
            out[base + 256 + n] = Zm[mt][q];
        }
    }
}

extern "C" void kernel_launch(void* const* d_in, const int* in_sizes, int n_in,
                              void* d_out, int out_size, void* d_ws, size_t ws_size,
                              hipStream_t stream) {
    (void)in_sizes; (void)n_in; (void)out_size;
    const float* Y0 = (const float*)d_in[0];
    const float* K  = (const float*)d_in[1];
    const float* b  = (const float*)d_in[2];

    const size_t ARR = (size_t)64 * 256 * 256;
    if (ws_size < 4 * ARR * sizeof(_Float16)) return;

    _Float16* B1h = (_Float16*)d_ws;
    _Float16* B1l = B1h + ARR;
    _Float16* B2h = B1l + ARR;
    _Float16* B2l = B2h + ARR;

    prep_split<<<512, 256, 0, stream>>>(K, B1h, B1l, B2h, B2l);
    ms1_main<<<256, 1024, 0, stream>>>(Y0, b, B1h, B1l, B2h, B2l, (float*)d_out);
}